// Round 16
// baseline (216.975 us; speedup 1.0000x reference)
//
#include <hip/hip_runtime.h>

typedef __bf16 bf16x8 __attribute__((ext_vector_type(8)));
typedef float f32x4 __attribute__((ext_vector_type(4)));
typedef unsigned u32x4 __attribute__((ext_vector_type(4)));
typedef unsigned short u16;

#define GAS __attribute__((address_space(1)))
#define LAS __attribute__((address_space(3)))

static __device__ __forceinline__ void gload16(const void* g, void* l) {
  __builtin_amdgcn_global_load_lds((const GAS unsigned int*)g, (LAS unsigned int*)l, 16, 0, 0);
}

static __device__ __forceinline__ u16 f2bf(float f) {
  unsigned u = __builtin_bit_cast(unsigned, f);
  u += 0x7fffu + ((u >> 16) & 1u);
  return (u16)(u >> 16);
}

static __device__ __forceinline__ unsigned pk2(float lo, float hi) {
  ushort2 u;
  u.x = __builtin_bit_cast(u16, (__bf16)lo);
  u.y = __builtin_bit_cast(u16, (__bf16)hi);
  return __builtin_bit_cast(unsigned, u);
}

// ---------------- fused fp32 -> bf16 convert ----------------
__global__ void cvt_all(const float* __restrict__ x, const float* __restrict__ wq,
                        const float* __restrict__ wk, const float* __restrict__ wv,
                        const float* __restrict__ wo, u16* __restrict__ xb,
                        u16* __restrict__ wqkvb, u16* __restrict__ wob) {
  int i = blockIdx.x * 256 + threadIdx.x;
  float4 v;
  ushort4* dst;
  if (i < 2097152) {
    v = reinterpret_cast<const float4*>(x)[i];
    dst = reinterpret_cast<ushort4*>(xb) + i;
  } else if (i < 2883584) {
    int j = i - 2097152;
    const float* s = j < 262144 ? wq : (j < 524288 ? wk : wv);
    int jj = j < 262144 ? j : (j < 524288 ? j - 262144 : j - 524288);
    v = reinterpret_cast<const float4*>(s)[jj];
    dst = reinterpret_cast<ushort4*>(wqkvb) + j;
  } else {
    int j = i - 2883584;
    v = reinterpret_cast<const float4*>(wo)[j];
    dst = reinterpret_cast<ushort4*>(wob) + j;
  }
  ushort4 o;
  o.x = f2bf(v.x); o.y = f2bf(v.y); o.z = f2bf(v.z); o.w = f2bf(v.w);
  *dst = o;
}

// ---------------- QKV GEMM: C[8192x3072] = X[8192x1024] @ Wqkv^T ----------------
// 2-deep (3-buffer) pipeline, vmcnt(4) counted waits. Staging uses uniform-base +
// 32-bit voffset addressing (saddr form): per-lane offsets are kt-invariant ints.
// V epilogue: sigma-permuted kv columns (16x16 PV layout).
__global__ void gemm_qkv(const u16* __restrict__ A, const u16* __restrict__ W,
                         u16* __restrict__ Qo, u16* __restrict__ Ko, u16* __restrict__ Vo) {
  __shared__ u16 As[3 * 128 * 32];
  __shared__ u16 Bs[3 * 128 * 32];
  const int t = threadIdx.x;
  const int lane = t & 63;
  const int w = t >> 6;
  const int wr = w >> 1, wc = w & 1;
  const int l15 = lane & 15, lhi = lane >> 4;
  const int swz = (blockIdx.x & 7) * 192 + (blockIdx.x >> 3);
  const int bm = swz / 24, bn = swz % 24;

  f32x4 acc[4][4];
#pragma unroll
  for (int a = 0; a < 4; ++a)
#pragma unroll
    for (int b = 0; b < 4; ++b) acc[a][b] = (f32x4){0.f, 0.f, 0.f, 0.f};

  // lane-constant 32-bit element offsets (uniform base A/W stays scalar -> saddr form)
  const int va = (bm * 128 + (t >> 2)) * 1024 + (t & 3) * 8;
  const int vb = (bn * 128 + (t >> 2)) * 1024 + (t & 3) * 8;

  auto stage = [&](int cb, int kt) {
    const int ko = kt * 32;
    gload16(A + va + ko, &As[cb + t * 8]);
    gload16(A + va + ko + 65536, &As[cb + t * 8 + 2048]);
    gload16(W + vb + ko, &Bs[cb + t * 8]);
    gload16(W + vb + ko + 65536, &Bs[cb + t * 8 + 2048]);
  };

  stage(0, 0);
  stage(4096, 1);
  asm volatile("s_waitcnt vmcnt(4)" ::: "memory");  // kt0 landed; kt1 in flight
  __builtin_amdgcn_s_barrier();

  int cur = 0, stg = 2;  // stg = (cur+2)%3
  for (int kt = 0; kt < 32; ++kt) {
    if (kt < 30) stage(stg * 4096, kt + 2);
    const int cb = cur * 4096;
    bf16x8 af[4], bfr[4];
#pragma unroll
    for (int mt = 0; mt < 4; ++mt)
      af[mt] = *(const bf16x8*)&As[cb + (wr * 64 + mt * 16 + l15) * 32 + lhi * 8];
#pragma unroll
    for (int nt = 0; nt < 4; ++nt)
      bfr[nt] = *(const bf16x8*)&Bs[cb + (wc * 64 + nt * 16 + l15) * 32 + lhi * 8];
#pragma unroll
    for (int mt = 0; mt < 4; ++mt)
#pragma unroll
      for (int nt = 0; nt < 4; ++nt)
        acc[mt][nt] = __builtin_amdgcn_mfma_f32_16x16x32_bf16(af[mt], bfr[nt], acc[mt][nt], 0, 0, 0);
    if (kt < 30) {
      asm volatile("s_waitcnt vmcnt(4)" ::: "memory");  // kt+1 landed; kt+2 in flight
    } else {
      asm volatile("s_waitcnt vmcnt(0)" ::: "memory");
    }
    __builtin_amdgcn_s_barrier();
    cur = (cur == 2) ? 0 : cur + 1;
    stg = (stg == 2) ? 0 : stg + 1;
  }

  const int tsel = bn >> 3;
  const int m0 = bm * 128 + wr * 64;
  const int n0 = bn * 128 + wc * 64;
  const int bb = bm >> 4;
  if (tsel == 0) {
    const float qs = 0.125f * 1.4426950408889634f;  // fold softmax scale + log2e
#pragma unroll
    for (int nt = 0; nt < 4; ++nt) {
      int n = n0 + nt * 16 + l15;
      int c = n & 1023, h = c >> 6, hd = c & 63;
      size_t base = (size_t)(bb * 16 + h) * 2048 * 64 + hd;
#pragma unroll
      for (int mt = 0; mt < 4; ++mt)
#pragma unroll
        for (int i = 0; i < 4; ++i) {
          int s = (m0 + mt * 16 + lhi * 4 + i) & 2047;
          Qo[base + (size_t)s * 64] = f2bf(acc[mt][nt][i] * qs);
        }
    }
  } else if (tsel == 1) {
#pragma unroll
    for (int nt = 0; nt < 4; ++nt) {
      int n = n0 + nt * 16 + l15;
      int c = n & 1023, h = c >> 6, hd = c & 63;
      size_t base = (size_t)(bb * 16 + h) * 2048 * 64 + hd;
#pragma unroll
      for (int mt = 0; mt < 4; ++mt)
#pragma unroll
        for (int i = 0; i < 4; ++i) {
          int s = (m0 + mt * 16 + lhi * 4 + i) & 2047;
          Ko[base + (size_t)s * 64] = f2bf(acc[mt][nt][i]);
        }
    }
  } else {
#pragma unroll
    for (int nt = 0; nt < 4; ++nt) {
      int n = n0 + nt * 16 + l15;
      int c = n & 1023, h = c >> 6, hd = c & 63;
#pragma unroll
      for (int mt = 0; mt < 4; ++mt) {
        int s0 = (m0 + mt * 16 + lhi * 4) & 2047;
        // sigma perm: bits [1:0] keep, [4]->[2], [3:2]->[4:3], [5+] keep
        int sp0 = ((s0 >> 4) & 1) * 4 + ((s0 >> 2) & 3) * 8 + (s0 >> 5) * 32;
        ushort4 pk;
        pk.x = f2bf(acc[mt][nt][0]);
        pk.y = f2bf(acc[mt][nt][1]);
        pk.z = f2bf(acc[mt][nt][2]);
        pk.w = f2bf(acc[mt][nt][3]);
        *(ushort4*)&Vo[((size_t)(bb * 16 + h) * 64 + hd) * 2048 + sp0] = pk;
      }
    }
  }
}

// ---------------- Flash attention: R10 structure + hoisted staging addresses ---------------
// 4 waves, 2 q-sets/wave, QBLK=128, KVBLK=64, grid 1024. Swapped QK^T, fixed-scale
// softmax (exp2 direct), sigma-permuted V, l via mfma(P, ones), setprio, single
// barrier per kt. Staging: uniform kp/vp base + loop-carried 32-bit voffsets
// (advanced by constants) -> saddr-form global_load_lds, ~0 VALU address math per kt.
__global__ __launch_bounds__(256, 4) void attn_kernel(const u16* __restrict__ Q,
                                                      const u16* __restrict__ K,
                                                      const u16* __restrict__ Vp,
                                                      u16* __restrict__ Ctx) {
  __shared__ u16 Ks[2 * 64 * 64];  // [buf][kv][d]
  __shared__ u16 Vs[2 * 64 * 64];  // [buf][hd][kv-perm]
  const int t = threadIdx.x;
  const int lane = t & 63;
  const int w = t >> 6;  // 4 waves
  const int l15 = lane & 15, lhi = lane >> 4;
  const int swz = (blockIdx.x & 7) * 128 + (blockIdx.x >> 3);  // grid 1024 = 8*128
  const int qt = swz & 15, pair = swz >> 4;
  const u16* qp = Q + (size_t)pair * 2048 * 64;
  const u16* kp = K + (size_t)pair * 2048 * 64;
  const u16* vp = Vp + (size_t)pair * 64 * 2048;

  const int qrA = qt * 128 + w * 32 + l15;  // q-set A; set B = +16
  bf16x8 qfA[2], qfB[2];
  qfA[0] = *(const bf16x8*)&qp[(size_t)qrA * 64 + lhi * 8];
  qfA[1] = *(const bf16x8*)&qp[(size_t)qrA * 64 + 32 + lhi * 8];
  qfB[0] = *(const bf16x8*)&qp[(size_t)(qrA + 16) * 64 + lhi * 8];
  qfB[1] = *(const bf16x8*)&qp[(size_t)(qrA + 16) * 64 + 32 + lhi * 8];

  const u32x4 ow = {0x3F803F80u, 0x3F803F80u, 0x3F803F80u, 0x3F803F80u};
  const bf16x8 onesf = __builtin_bit_cast(bf16x8, ow);

  const int swzq = (l15 & 7) << 3;
  const int kofs0 = l15 * 64 + ((lhi * 8) ^ swzq);
  const int kofs1 = l15 * 64 + ((32 + lhi * 8) ^ swzq);
  const int vofs0 = kofs0, vofs1 = kofs1;

  // lane-constant staging offsets: col = ((t&7)*8) ^ (((t>>3)&7)<<3)
  const int scol = ((t & 7) * 8) ^ (((t >> 3) & 7) << 3);
  int kvo = (t >> 3) * 64 + scol;    // K elem offset; += 4096 per kt (j-term +2048)
  int vvo = (t >> 3) * 2048 + scol;  // V elem offset; += 64 per kt (j-term +65536)

  f32x4 coA[4], coB[4], laA, laB;
  laA = (f32x4){0.f, 0.f, 0.f, 0.f};
  laB = laA;
#pragma unroll
  for (int n = 0; n < 4; ++n) { coA[n] = laA; coB[n] = laA; }

  auto stage = [&](int cb) {
    gload16(kp + kvo, &Ks[cb + t * 8]);
    gload16(kp + kvo + 2048, &Ks[cb + 2048 + t * 8]);
    gload16(vp + vvo, &Vs[cb + t * 8]);
    gload16(vp + vvo + 65536, &Vs[cb + 2048 + t * 8]);
    kvo += 4096;
    vvo += 64;
  };

  auto softmax_sub = [&](f32x4 (&sa)[4], unsigned (&pw)[4][2]) {
#pragma unroll
    for (int nt = 0; nt < 4; ++nt)
#pragma unroll
      for (int e = 0; e < 4; ++e) sa[nt][e] = __builtin_exp2f(sa[nt][e]);
#pragma unroll
    for (int nt = 0; nt < 4; ++nt) {
      pw[nt][0] = pk2(sa[nt][0], sa[nt][1]);
      pw[nt][1] = pk2(sa[nt][2], sa[nt][3]);
    }
  };

  stage(0);
  asm volatile("s_waitcnt vmcnt(0)" ::: "memory");
  __builtin_amdgcn_s_barrier();

  for (int kt = 0; kt < 32; ++kt) {
    const int cb = (kt & 1) * 4096;
    if (kt < 31) stage(cb ^ 4096);  // issue early; drained at loop bottom

    // ---- QK^T (swapped), kf shared by both q-sets ----
    f32x4 saA[4], saB[4];
    __builtin_amdgcn_s_setprio(1);
#pragma unroll
    for (int nt = 0; nt < 4; ++nt) {
      bf16x8 kf0 = *(const bf16x8*)&Ks[cb + kofs0 + nt * 1024];
      bf16x8 kf1 = *(const bf16x8*)&Ks[cb + kofs1 + nt * 1024];
      f32x4 zA = (f32x4){0.f, 0.f, 0.f, 0.f};
      f32x4 zB = zA;
      zA = __builtin_amdgcn_mfma_f32_16x16x32_bf16(kf0, qfA[0], zA, 0, 0, 0);
      zB = __builtin_amdgcn_mfma_f32_16x16x32_bf16(kf0, qfB[0], zB, 0, 0, 0);
      saA[nt] = __builtin_amdgcn_mfma_f32_16x16x32_bf16(kf1, qfA[1], zA, 0, 0, 0);
      saB[nt] = __builtin_amdgcn_mfma_f32_16x16x32_bf16(kf1, qfB[1], zB, 0, 0, 0);
    }
    __builtin_amdgcn_s_setprio(0);

    unsigned pwA[4][2], pwB[4][2];
    softmax_sub(saA, pwA);
    softmax_sub(saB, pwB);

    // ---- PV + l-sum ----
    __builtin_amdgcn_s_setprio(1);
#pragma unroll
    for (int ks = 0; ks < 2; ++ks) {
      u32x4 awA = {pwA[2 * ks][0], pwA[2 * ks][1], pwA[2 * ks + 1][0], pwA[2 * ks + 1][1]};
      u32x4 awB = {pwB[2 * ks][0], pwB[2 * ks][1], pwB[2 * ks + 1][0], pwB[2 * ks + 1][1]};
      bf16x8 afA = __builtin_bit_cast(bf16x8, awA);
      bf16x8 afB = __builtin_bit_cast(bf16x8, awB);
      laA = __builtin_amdgcn_mfma_f32_16x16x32_bf16(afA, onesf, laA, 0, 0, 0);
      laB = __builtin_amdgcn_mfma_f32_16x16x32_bf16(afB, onesf, laB, 0, 0, 0);
      const int vo = ks ? vofs1 : vofs0;
#pragma unroll
      for (int nthd = 0; nthd < 4; ++nthd) {
        bf16x8 vf = *(const bf16x8*)&Vs[cb + vo + nthd * 1024];
        coA[nthd] = __builtin_amdgcn_mfma_f32_16x16x32_bf16(afA, vf, coA[nthd], 0, 0, 0);
        coB[nthd] = __builtin_amdgcn_mfma_f32_16x16x32_bf16(afB, vf, coB[nthd], 0, 0, 0);
      }
    }
    __builtin_amdgcn_s_setprio(0);

    asm volatile("s_waitcnt vmcnt(0)" ::: "memory");  // stage(t+1) drained (hidden)
    __builtin_amdgcn_s_barrier();                      // single barrier per kt
  }

  // ---- epilogue: out = co / la ----
  float liA[4], liB[4];
#pragma unroll
  for (int i = 0; i < 4; ++i) {
    liA[i] = 1.0f / laA[i];
    liB[i] = 1.0f / laB[i];
  }
  const int bb = pair >> 4, hh = pair & 15;
  const int sbase = qt * 128 + w * 32 + lhi * 4;
#pragma unroll
  for (int nthd = 0; nthd < 4; ++nthd) {
    int hd = nthd * 16 + l15;
#pragma unroll
    for (int i = 0; i < 4; ++i) {
      Ctx[(size_t)(bb * 2048 + sbase + i) * 1024 + hh * 64 + hd] = f2bf(coA[nthd][i] * liA[i]);
      Ctx[(size_t)(bb * 2048 + sbase + 16 + i) * 1024 + hh * 64 + hd] = f2bf(coB[nthd][i] * liB[i]);
    }
  }
}

// ---------------- Output GEMM: out[8192x1024] = Ctx @ Wo^T + bo (fp32 out) ----------------
// 128x64 tiles, grid 1024 (4/CU), 2-deep 3-buffer pipeline, saddr-form staging.
__global__ void gemm_out(const u16* __restrict__ A, const u16* __restrict__ W,
                         const float* __restrict__ Bo, float* __restrict__ Out) {
  __shared__ u16 As[3 * 128 * 32];
  __shared__ u16 Bs[3 * 64 * 32];
  const int t = threadIdx.x;
  const int lane = t & 63;
  const int w = t >> 6;
  const int wr = w >> 1, wc = w & 1;
  const int l15 = lane & 15, lhi = lane >> 4;
  const int swz = (blockIdx.x & 7) * 128 + (blockIdx.x >> 3);  // grid 1024 = 8*128
  const int bm = swz >> 4, bn = swz & 15;

  f32x4 acc[4][2];
#pragma unroll
  for (int a = 0; a < 4; ++a)
#pragma unroll
    for (int b = 0; b < 2; ++b) acc[a][b] = (f32x4){0.f, 0.f, 0.f, 0.f};

  const int va = (bm * 128 + (t >> 2)) * 1024 + (t & 3) * 8;
  const int vb = (bn * 64 + (t >> 2)) * 1024 + (t & 3) * 8;

  auto stage = [&](int cba, int cbb, int kt) {
    const int ko = kt * 32;
    gload16(A + va + ko, &As[cba + t * 8]);
    gload16(A + va + ko + 65536, &As[cba + t * 8 + 2048]);
    gload16(W + vb + ko, &Bs[cbb + t * 8]);
  };

  stage(0, 0, 0);
  stage(4096, 2048, 1);
  asm volatile("s_waitcnt vmcnt(3)" ::: "memory");  // kt0 landed; kt1 in flight
  __builtin_amdgcn_s_barrier();

  int cur = 0, stg = 2;
  for (int kt = 0; kt < 32; ++kt) {
    if (kt < 30) stage(stg * 4096, stg * 2048, kt + 2);
    const int cba = cur * 4096, cbb = cur * 2048;
    bf16x8 af[4], bfr[2];
#pragma unroll
    for (int mt = 0; mt < 4; ++mt)
      af[mt] = *(const bf16x8*)&As[cba + (wr * 64 + mt * 16 + l15) * 32 + lhi * 8];
#pragma unroll
    for (int nt = 0; nt < 2; ++nt)
      bfr[nt] = *(const bf16x8*)&Bs[cbb + (wc * 32 + nt * 16 + l15) * 32 + lhi * 8];
#pragma unroll
    for (int mt = 0; mt < 4; ++mt)
#pragma unroll
      for (int nt = 0; nt < 2; ++nt)
        acc[mt][nt] = __builtin_amdgcn_mfma_f32_16x16x32_bf16(af[mt], bfr[nt], acc[mt][nt], 0, 0, 0);
    if (kt < 30) {
      asm volatile("s_waitcnt vmcnt(3)" ::: "memory");
    } else {
      asm volatile("s_waitcnt vmcnt(0)" ::: "memory");
    }
    __builtin_amdgcn_s_barrier();
    cur = (cur == 2) ? 0 : cur + 1;
    stg = (stg == 2) ? 0 : stg + 1;
  }

  const int m0 = bm * 128 + wr * 64;
  const int n0 = bn * 64 + wc * 32;
#pragma unroll
  for (int nt = 0; nt < 2; ++nt) {
    int n = n0 + nt * 16 + l15;
    float bias = Bo[n];
#pragma unroll
    for (int mt = 0; mt < 4; ++mt)
#pragma unroll
      for (int i = 0; i < 4; ++i) {
        int m = m0 + mt * 16 + lhi * 4 + i;
        Out[(size_t)m * 1024 + n] = acc[mt][nt][i] + bias;
      }
  }
}

// ---------------- launch ----------------
extern "C" void kernel_launch(void* const* d_in, const int* in_sizes, int n_in,
                              void* d_out, int out_size, void* d_ws, size_t ws_size,
                              hipStream_t stream) {
  const float* x  = (const float*)d_in[0];
  const float* wq = (const float*)d_in[1];
  const float* wk = (const float*)d_in[2];
  const float* wv = (const float*)d_in[3];
  const float* wo = (const float*)d_in[4];
  const float* bo = (const float*)d_in[5];
  float* out = (float*)d_out;

  u16* xb    = (u16*)d_ws;                      // 8M elems
  u16* wqkvb = xb + (size_t)8 * 1024 * 1024;    // 3M
  u16* wob   = wqkvb + (size_t)3 * 1024 * 1024; // 1M
  u16* qb    = wob + (size_t)1 * 1024 * 1024;   // 8M
  u16* kb    = qb + (size_t)8 * 1024 * 1024;    // 8M
  u16* vtb   = kb + (size_t)8 * 1024 * 1024;    // 8M (sigma-permuted V^T)
  u16* ctxb  = xb;                              // alias: xb dead after gemm_qkv

  cvt_all<<<12288, 256, 0, stream>>>(x, wq, wk, wv, wo, xb, wqkvb, wob);
  gemm_qkv<<<64 * 24, 256, 0, stream>>>(xb, wqkvb, qb, kb, vtb);
  attn_kernel<<<1024, 256, 0, stream>>>(qb, kb, vtb, ctxb);
  gemm_out<<<1024, 256, 0, stream>>>(ctxb, wob, bo, out);
}

// Round 18
// 214.311 us; speedup vs baseline: 1.0124x; 1.0124x over previous
//
#include <hip/hip_runtime.h>

typedef __bf16 bf16x8 __attribute__((ext_vector_type(8)));
typedef float f32x4 __attribute__((ext_vector_type(4)));
typedef unsigned u32x4 __attribute__((ext_vector_type(4)));
typedef unsigned short u16;

#define GAS __attribute__((address_space(1)))
#define LAS __attribute__((address_space(3)))

static __device__ __forceinline__ void gload16(const void* g, void* l) {
  __builtin_amdgcn_global_load_lds((const GAS unsigned int*)g, (LAS unsigned int*)l, 16, 0, 0);
}

static __device__ __forceinline__ u16 f2bf(float f) {
  unsigned u = __builtin_bit_cast(unsigned, f);
  u += 0x7fffu + ((u >> 16) & 1u);
  return (u16)(u >> 16);
}

static __device__ __forceinline__ unsigned pk2(float lo, float hi) {
  ushort2 u;
  u.x = __builtin_bit_cast(u16, (__bf16)lo);
  u.y = __builtin_bit_cast(u16, (__bf16)hi);
  return __builtin_bit_cast(unsigned, u);
}

// ---------------- fused fp32 -> bf16 convert ----------------
__global__ void cvt_all(const float* __restrict__ x, const float* __restrict__ wq,
                        const float* __restrict__ wk, const float* __restrict__ wv,
                        const float* __restrict__ wo, u16* __restrict__ xb,
                        u16* __restrict__ wqkvb, u16* __restrict__ wob) {
  int i = blockIdx.x * 256 + threadIdx.x;
  float4 v;
  ushort4* dst;
  if (i < 2097152) {
    v = reinterpret_cast<const float4*>(x)[i];
    dst = reinterpret_cast<ushort4*>(xb) + i;
  } else if (i < 2883584) {
    int j = i - 2097152;
    const float* s = j < 262144 ? wq : (j < 524288 ? wk : wv);
    int jj = j < 262144 ? j : (j < 524288 ? j - 262144 : j - 524288);
    v = reinterpret_cast<const float4*>(s)[jj];
    dst = reinterpret_cast<ushort4*>(wqkvb) + j;
  } else {
    int j = i - 2883584;
    v = reinterpret_cast<const float4*>(wo)[j];
    dst = reinterpret_cast<ushort4*>(wob) + j;
  }
  ushort4 o;
  o.x = f2bf(v.x); o.y = f2bf(v.y); o.z = f2bf(v.z); o.w = f2bf(v.w);
  *dst = o;
}

// ---------------- QKV GEMM: C[8192x3072] = X[8192x1024] @ Wqkv^T ----------------
// 2-deep (3-buffer) pipeline: stage(kt+2) issued at top of kt; bottom waits vmcnt(4)
// (= kt+1's loads, issued a FULL iteration earlier -> HBM latency covered by ~2 kt of
// compute); kt+2's 4 loads stay in flight across the barrier. Never vmcnt(0) mid-loop.
// V epilogue: sigma-permuted kv columns (16x16 PV layout).
__global__ void gemm_qkv(const u16* __restrict__ A, const u16* __restrict__ W,
                         u16* __restrict__ Qo, u16* __restrict__ Ko, u16* __restrict__ Vo) {
  __shared__ u16 As[3 * 128 * 32];
  __shared__ u16 Bs[3 * 128 * 32];
  const int t = threadIdx.x;
  const int lane = t & 63;
  const int w = t >> 6;
  const int wr = w >> 1, wc = w & 1;
  const int l15 = lane & 15, lhi = lane >> 4;
  const int swz = (blockIdx.x & 7) * 192 + (blockIdx.x >> 3);
  const int bm = swz / 24, bn = swz % 24;

  f32x4 acc[4][4];
#pragma unroll
  for (int a = 0; a < 4; ++a)
#pragma unroll
    for (int b = 0; b < 4; ++b) acc[a][b] = (f32x4){0.f, 0.f, 0.f, 0.f};

  const u16* ag = A + (size_t)(bm * 128 + (t >> 2)) * 1024 + (t & 3) * 8;
  const u16* bg = W + (size_t)(bn * 128 + (t >> 2)) * 1024 + (t & 3) * 8;

  auto stage = [&](int cb, int kt) {
    gload16(ag + kt * 32, &As[cb + t * 8]);
    gload16(ag + kt * 32 + 64 * 1024, &As[cb + t * 8 + 2048]);
    gload16(bg + kt * 32, &Bs[cb + t * 8]);
    gload16(bg + kt * 32 + 64 * 1024, &Bs[cb + t * 8 + 2048]);
  };

  stage(0, 0);
  stage(4096, 1);
  asm volatile("s_waitcnt vmcnt(4)" ::: "memory");  // kt0 landed; kt1 in flight
  __builtin_amdgcn_s_barrier();

  int cur = 0, stg = 2;  // stg = (cur+2)%3
  for (int kt = 0; kt < 32; ++kt) {
    if (kt < 30) stage(stg * 4096, kt + 2);
    const int cb = cur * 4096;
    bf16x8 af[4], bfr[4];
#pragma unroll
    for (int mt = 0; mt < 4; ++mt)
      af[mt] = *(const bf16x8*)&As[cb + (wr * 64 + mt * 16 + l15) * 32 + lhi * 8];
#pragma unroll
    for (int nt = 0; nt < 4; ++nt)
      bfr[nt] = *(const bf16x8*)&Bs[cb + (wc * 64 + nt * 16 + l15) * 32 + lhi * 8];
#pragma unroll
    for (int mt = 0; mt < 4; ++mt)
#pragma unroll
      for (int nt = 0; nt < 4; ++nt)
        acc[mt][nt] = __builtin_amdgcn_mfma_f32_16x16x32_bf16(af[mt], bfr[nt], acc[mt][nt], 0, 0, 0);
    if (kt < 30) {
      asm volatile("s_waitcnt vmcnt(4)" ::: "memory");  // kt+1 landed; kt+2 in flight
    } else {
      asm volatile("s_waitcnt vmcnt(0)" ::: "memory");
    }
    __builtin_amdgcn_s_barrier();
    cur = (cur == 2) ? 0 : cur + 1;
    stg = (stg == 2) ? 0 : stg + 1;
  }

  const int tsel = bn >> 3;
  const int m0 = bm * 128 + wr * 64;
  const int n0 = bn * 128 + wc * 64;
  const int bb = bm >> 4;
  if (tsel == 0) {
    const float qs = 0.125f * 1.4426950408889634f;  // fold softmax scale + log2e
#pragma unroll
    for (int nt = 0; nt < 4; ++nt) {
      int n = n0 + nt * 16 + l15;
      int c = n & 1023, h = c >> 6, hd = c & 63;
      size_t base = (size_t)(bb * 16 + h) * 2048 * 64 + hd;
#pragma unroll
      for (int mt = 0; mt < 4; ++mt)
#pragma unroll
        for (int i = 0; i < 4; ++i) {
          int s = (m0 + mt * 16 + lhi * 4 + i) & 2047;
          Qo[base + (size_t)s * 64] = f2bf(acc[mt][nt][i] * qs);
        }
    }
  } else if (tsel == 1) {
#pragma unroll
    for (int nt = 0; nt < 4; ++nt) {
      int n = n0 + nt * 16 + l15;
      int c = n & 1023, h = c >> 6, hd = c & 63;
      size_t base = (size_t)(bb * 16 + h) * 2048 * 64 + hd;
#pragma unroll
      for (int mt = 0; mt < 4; ++mt)
#pragma unroll
        for (int i = 0; i < 4; ++i) {
          int s = (m0 + mt * 16 + lhi * 4 + i) & 2047;
          Ko[base + (size_t)s * 64] = f2bf(acc[mt][nt][i]);
        }
    }
  } else {
#pragma unroll
    for (int nt = 0; nt < 4; ++nt) {
      int n = n0 + nt * 16 + l15;
      int c = n & 1023, h = c >> 6, hd = c & 63;
#pragma unroll
      for (int mt = 0; mt < 4; ++mt) {
        int s0 = (m0 + mt * 16 + lhi * 4) & 2047;
        // sigma perm: bits [1:0] keep, [4]->[2], [3:2]->[4:3], [5+] keep
        int sp0 = ((s0 >> 4) & 1) * 4 + ((s0 >> 2) & 3) * 8 + (s0 >> 5) * 32;
        ushort4 pk;
        pk.x = f2bf(acc[mt][nt][0]);
        pk.y = f2bf(acc[mt][nt][1]);
        pk.z = f2bf(acc[mt][nt][2]);
        pk.w = f2bf(acc[mt][nt][3]);
        *(ushort4*)&Vo[((size_t)(bb * 16 + h) * 64 + hd) * 2048 + sp0] = pk;
      }
    }
  }
}

// ---------------- Flash attention: R10 structure (final; ~122.5 us floor) ----------------
// 4 waves, 2 q-sets/wave, QBLK=128, KVBLK=64, grid 1024. Swapped QK^T, fixed-scale
// softmax (exp2 direct), sigma-permuted V, l via mfma(P, ones), setprio around MFMA
// clusters, single barrier per kt with stage issued early.
__global__ __launch_bounds__(256, 4) void attn_kernel(const u16* __restrict__ Q,
                                                      const u16* __restrict__ K,
                                                      const u16* __restrict__ Vp,
                                                      u16* __restrict__ Ctx) {
  __shared__ u16 Ks[2 * 64 * 64];  // [buf][kv][d]
  __shared__ u16 Vs[2 * 64 * 64];  // [buf][hd][kv-perm]
  const int t = threadIdx.x;
  const int lane = t & 63;
  const int w = t >> 6;  // 4 waves
  const int l15 = lane & 15, lhi = lane >> 4;
  const int swz = (blockIdx.x & 7) * 128 + (blockIdx.x >> 3);  // grid 1024 = 8*128
  const int qt = swz & 15, pair = swz >> 4;
  const u16* qp = Q + (size_t)pair * 2048 * 64;
  const u16* kp = K + (size_t)pair * 2048 * 64;
  const u16* vp = Vp + (size_t)pair * 64 * 2048;

  const int qrA = qt * 128 + w * 32 + l15;  // q-set A; set B = +16
  bf16x8 qfA[2], qfB[2];
  qfA[0] = *(const bf16x8*)&qp[(size_t)qrA * 64 + lhi * 8];
  qfA[1] = *(const bf16x8*)&qp[(size_t)qrA * 64 + 32 + lhi * 8];
  qfB[0] = *(const bf16x8*)&qp[(size_t)(qrA + 16) * 64 + lhi * 8];
  qfB[1] = *(const bf16x8*)&qp[(size_t)(qrA + 16) * 64 + 32 + lhi * 8];

  const u32x4 ow = {0x3F803F80u, 0x3F803F80u, 0x3F803F80u, 0x3F803F80u};
  const bf16x8 onesf = __builtin_bit_cast(bf16x8, ow);

  const int swzq = (l15 & 7) << 3;
  const int kofs0 = l15 * 64 + ((lhi * 8) ^ swzq);
  const int kofs1 = l15 * 64 + ((32 + lhi * 8) ^ swzq);
  const int vofs0 = kofs0, vofs1 = kofs1;

  f32x4 coA[4], coB[4], laA, laB;
  laA = (f32x4){0.f, 0.f, 0.f, 0.f};
  laB = laA;
#pragma unroll
  for (int n = 0; n < 4; ++n) { coA[n] = laA; coB[n] = laA; }

  auto stage = [&](int cb, int tt) {
#pragma unroll
    for (int j = 0; j < 2; ++j) {
      int c = j * 256 + t;
      int r = c >> 3, c8 = (c & 7) * 8;
      gload16(kp + (size_t)(tt * 64 + r) * 64 + (c8 ^ ((r & 7) << 3)), &Ks[cb + c * 8]);
    }
#pragma unroll
    for (int j = 0; j < 2; ++j) {
      int c = j * 256 + t;
      int r = c >> 3, c8 = (c & 7) * 8;
      gload16(vp + (size_t)r * 2048 + tt * 64 + (c8 ^ ((r & 7) << 3)), &Vs[cb + c * 8]);
    }
  };

  auto softmax_sub = [&](f32x4 (&sa)[4], unsigned (&pw)[4][2]) {
#pragma unroll
    for (int nt = 0; nt < 4; ++nt)
#pragma unroll
      for (int e = 0; e < 4; ++e) sa[nt][e] = __builtin_exp2f(sa[nt][e]);
#pragma unroll
    for (int nt = 0; nt < 4; ++nt) {
      pw[nt][0] = pk2(sa[nt][0], sa[nt][1]);
      pw[nt][1] = pk2(sa[nt][2], sa[nt][3]);
    }
  };

  stage(0, 0);
  asm volatile("s_waitcnt vmcnt(0)" ::: "memory");
  __builtin_amdgcn_s_barrier();

  for (int kt = 0; kt < 32; ++kt) {
    const int cb = (kt & 1) * 4096;
    if (kt < 31) stage(cb ^ 4096, kt + 1);  // issue early; drained at loop bottom

    // ---- QK^T (swapped), kf shared by both q-sets ----
    f32x4 saA[4], saB[4];
    __builtin_amdgcn_s_setprio(1);
#pragma unroll
    for (int nt = 0; nt < 4; ++nt) {
      bf16x8 kf0 = *(const bf16x8*)&Ks[cb + kofs0 + nt * 1024];
      bf16x8 kf1 = *(const bf16x8*)&Ks[cb + kofs1 + nt * 1024];
      f32x4 zA = (f32x4){0.f, 0.f, 0.f, 0.f};
      f32x4 zB = zA;
      zA = __builtin_amdgcn_mfma_f32_16x16x32_bf16(kf0, qfA[0], zA, 0, 0, 0);
      zB = __builtin_amdgcn_mfma_f32_16x16x32_bf16(kf0, qfB[0], zB, 0, 0, 0);
      saA[nt] = __builtin_amdgcn_mfma_f32_16x16x32_bf16(kf1, qfA[1], zA, 0, 0, 0);
      saB[nt] = __builtin_amdgcn_mfma_f32_16x16x32_bf16(kf1, qfB[1], zB, 0, 0, 0);
    }
    __builtin_amdgcn_s_setprio(0);

    unsigned pwA[4][2], pwB[4][2];
    softmax_sub(saA, pwA);
    softmax_sub(saB, pwB);

    // ---- PV + l-sum ----
    __builtin_amdgcn_s_setprio(1);
#pragma unroll
    for (int ks = 0; ks < 2; ++ks) {
      u32x4 awA = {pwA[2 * ks][0], pwA[2 * ks][1], pwA[2 * ks + 1][0], pwA[2 * ks + 1][1]};
      u32x4 awB = {pwB[2 * ks][0], pwB[2 * ks][1], pwB[2 * ks + 1][0], pwB[2 * ks + 1][1]};
      bf16x8 afA = __builtin_bit_cast(bf16x8, awA);
      bf16x8 afB = __builtin_bit_cast(bf16x8, awB);
      laA = __builtin_amdgcn_mfma_f32_16x16x32_bf16(afA, onesf, laA, 0, 0, 0);
      laB = __builtin_amdgcn_mfma_f32_16x16x32_bf16(afB, onesf, laB, 0, 0, 0);
      const int vo = ks ? vofs1 : vofs0;
#pragma unroll
      for (int nthd = 0; nthd < 4; ++nthd) {
        bf16x8 vf = *(const bf16x8*)&Vs[cb + vo + nthd * 1024];
        coA[nthd] = __builtin_amdgcn_mfma_f32_16x16x32_bf16(afA, vf, coA[nthd], 0, 0, 0);
        coB[nthd] = __builtin_amdgcn_mfma_f32_16x16x32_bf16(afB, vf, coB[nthd], 0, 0, 0);
      }
    }
    __builtin_amdgcn_s_setprio(0);

    asm volatile("s_waitcnt vmcnt(0)" ::: "memory");  // stage(t+1) drained (hidden)
    __builtin_amdgcn_s_barrier();                      // single barrier per kt
  }

  // ---- epilogue: out = co / la ----
  float liA[4], liB[4];
#pragma unroll
  for (int i = 0; i < 4; ++i) {
    liA[i] = 1.0f / laA[i];
    liB[i] = 1.0f / laB[i];
  }
  const int bb = pair >> 4, hh = pair & 15;
  const int sbase = qt * 128 + w * 32 + lhi * 4;
#pragma unroll
  for (int nthd = 0; nthd < 4; ++nthd) {
    int hd = nthd * 16 + l15;
#pragma unroll
    for (int i = 0; i < 4; ++i) {
      Ctx[(size_t)(bb * 2048 + sbase + i) * 1024 + hh * 64 + hd] = f2bf(coA[nthd][i] * liA[i]);
      Ctx[(size_t)(bb * 2048 + sbase + 16 + i) * 1024 + hh * 64 + hd] = f2bf(coB[nthd][i] * liB[i]);
    }
  }
}

// ---------------- Output GEMM: out[8192x1024] = Ctx @ Wo^T + bo (fp32 out) ----------------
// 128x64 tiles, grid 1024 (4/CU). Same 2-deep 3-buffer pipeline as gemm_qkv (3 loads/kt).
__global__ void gemm_out(const u16* __restrict__ A, const u16* __restrict__ W,
                         const float* __restrict__ Bo, float* __restrict__ Out) {
  __shared__ u16 As[3 * 128 * 32];
  __shared__ u16 Bs[3 * 64 * 32];
  const int t = threadIdx.x;
  const int lane = t & 63;
  const int w = t >> 6;
  const int wr = w >> 1, wc = w & 1;
  const int l15 = lane & 15, lhi = lane >> 4;
  const int swz = (blockIdx.x & 7) * 128 + (blockIdx.x >> 3);  // grid 1024 = 8*128
  const int bm = swz >> 4, bn = swz & 15;

  f32x4 acc[4][2];
#pragma unroll
  for (int a = 0; a < 4; ++a)
#pragma unroll
    for (int b = 0; b < 2; ++b) acc[a][b] = (f32x4){0.f, 0.f, 0.f, 0.f};

  const u16* ag = A + (size_t)(bm * 128 + (t >> 2)) * 1024 + (t & 3) * 8;
  const u16* bg = W + (size_t)(bn * 64 + (t >> 2)) * 1024 + (t & 3) * 8;

  auto stage = [&](int cba, int cbb, int kt) {
    gload16(ag + kt * 32, &As[cba + t * 8]);
    gload16(ag + kt * 32 + 64 * 1024, &As[cba + t * 8 + 2048]);
    gload16(bg + kt * 32, &Bs[cbb + t * 8]);
  };

  stage(0, 0, 0);
  stage(4096, 2048, 1);
  asm volatile("s_waitcnt vmcnt(3)" ::: "memory");  // kt0 landed; kt1 in flight
  __builtin_amdgcn_s_barrier();

  int cur = 0, stg = 2;
  for (int kt = 0; kt < 32; ++kt) {
    if (kt < 30) stage(stg * 4096, stg * 2048, kt + 2);
    const int cba = cur * 4096, cbb = cur * 2048;
    bf16x8 af[4], bfr[2];
#pragma unroll
    for (int mt = 0; mt < 4; ++mt)
      af[mt] = *(const bf16x8*)&As[cba + (wr * 64 + mt * 16 + l15) * 32 + lhi * 8];
#pragma unroll
    for (int nt = 0; nt < 2; ++nt)
      bfr[nt] = *(const bf16x8*)&Bs[cbb + (wc * 32 + nt * 16 + l15) * 32 + lhi * 8];
#pragma unroll
    for (int mt = 0; mt < 4; ++mt)
#pragma unroll
      for (int nt = 0; nt < 2; ++nt)
        acc[mt][nt] = __builtin_amdgcn_mfma_f32_16x16x32_bf16(af[mt], bfr[nt], acc[mt][nt], 0, 0, 0);
    if (kt < 30) {
      asm volatile("s_waitcnt vmcnt(3)" ::: "memory");
    } else {
      asm volatile("s_waitcnt vmcnt(0)" ::: "memory");
    }
    __builtin_amdgcn_s_barrier();
    cur = (cur == 2) ? 0 : cur + 1;
    stg = (stg == 2) ? 0 : stg + 1;
  }

  const int m0 = bm * 128 + wr * 64;
  const int n0 = bn * 64 + wc * 32;
#pragma unroll
  for (int nt = 0; nt < 2; ++nt) {
    int n = n0 + nt * 16 + l15;
    float bias = Bo[n];
#pragma unroll
    for (int mt = 0; mt < 4; ++mt)
#pragma unroll
      for (int i = 0; i < 4; ++i) {
        int m = m0 + mt * 16 + lhi * 4 + i;
        Out[(size_t)m * 1024 + n] = acc[mt][nt][i] + bias;
      }
  }
}

// ---------------- launch ----------------
extern "C" void kernel_launch(void* const* d_in, const int* in_sizes, int n_in,
                              void* d_out, int out_size, void* d_ws, size_t ws_size,
                              hipStream_t stream) {
  const float* x  = (const float*)d_in[0];
  const float* wq = (const float*)d_in[1];
  const float* wk = (const float*)d_in[2];
  const float* wv = (const float*)d_in[3];
  const float* wo = (const float*)d_in[4];
  const float* bo = (const float*)d_in[5];
  float* out = (float*)d_out;

  u16* xb    = (u16*)d_ws;                      // 8M elems
  u16* wqkvb = xb + (size_t)8 * 1024 * 1024;    // 3M
  u16* wob   = wqkvb + (size_t)3 * 1024 * 1024; // 1M
  u16* qb    = wob + (size_t)1 * 1024 * 1024;   // 8M
  u16* kb    = qb + (size_t)8 * 1024 * 1024;    // 8M
  u16* vtb   = kb + (size_t)8 * 1024 * 1024;    // 8M (sigma-permuted V^T)
  u16* ctxb  = xb;                              // alias: xb dead after gemm_qkv

  cvt_all<<<12288, 256, 0, stream>>>(x, wq, wk, wv, wo, xb, wqkvb, wob);
  gemm_qkv<<<64 * 24, 256, 0, stream>>>(xb, wqkvb, qb, kb, vtb);
  attn_kernel<<<1024, 256, 0, stream>>>(qb, kb, vtb, ctxb);
  gemm_out<<<1024, 256, 0, stream>>>(ctxb, wob, bo, out);
}